// Round 1
// baseline (1281.515 us; speedup 1.0000x reference)
//
#include <hip/hip_runtime.h>

typedef unsigned short u16;
typedef __attribute__((ext_vector_type(8))) short short8;
typedef __attribute__((ext_vector_type(4))) float f32x4;
typedef __attribute__((ext_vector_type(4))) unsigned short u16x4;

#define SEQ 2048
#define DM 1024
#define NTOK 8192  // B*L

__device__ __forceinline__ float b2f(u16 u) {
  union { float f; unsigned int i; } x; x.i = ((unsigned int)u) << 16; return x.f;
}
__device__ __forceinline__ u16 f2b(float f) {
  union { float f; unsigned int i; } x; x.f = f;
  unsigned int i = x.i;
  unsigned int r = (i + 0x7FFFu + ((i >> 16) & 1u)) >> 16;
  return (u16)r;
}

__device__ __forceinline__ void gload16(const u16* g, u16* l) {
  __builtin_amdgcn_global_load_lds(
      (const __attribute__((address_space(1))) void*)g,
      (__attribute__((address_space(3))) void*)l, 16, 0, 0);
}

// ---------------- weight transpose f32 (K x N) -> bf16 (N x K) ----------------
__global__ __launch_bounds__(256)
void wtrans(const float* __restrict__ in, u16* __restrict__ out,
            int K, int N, int rowOff, int ldOut)
{
  __shared__ float tile[32][33];
  const int n0 = blockIdx.x * 32;
  const int k0 = blockIdx.y * 32;
  const int tx = threadIdx.x, ty = threadIdx.y;
#pragma unroll
  for (int i = 0; i < 32; i += 8) {
    int k = k0 + ty + i, n = n0 + tx;
    tile[ty + i][tx] = (k < K && n < N) ? in[(long)k * N + n] : 0.f;
  }
  __syncthreads();
#pragma unroll
  for (int i = 0; i < 32; i += 8) {
    int n = n0 + ty + i, k = k0 + tx;
    if (n < N && k < K) out[(long)(rowOff + n) * ldOut + k] = f2b(tile[tx][ty + i]);
  }
}

// Bp_w/Cp_w (1024x16) -> rows [1024..1055] of WcatT (ld 1024)
__global__ __launch_bounds__(256)
void small_trans(const float* __restrict__ Bp, const float* __restrict__ Cp,
                 u16* __restrict__ wcatT)
{
  int t = blockIdx.x * 256 + threadIdx.x;  // 16384 threads
  int n = t >> 10, k = t & 1023;
  wcatT[(long)(1024 + n) * 1024 + k] = f2b(Bp[(long)k * 16 + n]);
  wcatT[(long)(1040 + n) * 1024 + k] = f2b(Cp[(long)k * 16 + n]);
}

// ---------------- LayerNorm helpers ----------------
__device__ __forceinline__ void blockReduce2(float& a, float& b, float* s)
{
#pragma unroll
  for (int off = 32; off > 0; off >>= 1) {
    a += __shfl_xor(a, off);
    b += __shfl_xor(b, off);
  }
  const int lane = threadIdx.x & 63, wid = threadIdx.x >> 6;
  __syncthreads();
  if (lane == 0) { s[wid] = a; s[4 + wid] = b; }
  __syncthreads();
  a = s[0] + s[1] + s[2] + s[3];
  b = s[4] + s[5] + s[6] + s[7];
}

// fused LN1 -> LN2, f32 in, bf16 out (row length 1024, 256 thr x 4 elems)
__global__ __launch_bounds__(256)
void ln_ln_kernel(const float* __restrict__ x, const float* __restrict__ g1,
                  const float* __restrict__ b1, const float* __restrict__ g2,
                  const float* __restrict__ b2, u16* __restrict__ out)
{
  __shared__ float sred[8];
  const long row = blockIdx.x;
  const int t = threadIdx.x;
  const float4 xv = ((const float4*)(x + row * DM))[t];
  float s = xv.x + xv.y + xv.z + xv.w;
  float sq = xv.x * xv.x + xv.y * xv.y + xv.z * xv.z + xv.w * xv.w;
  blockReduce2(s, sq, sred);
  const float mu = s * (1.f / DM);
  const float rs = rsqrtf(sq * (1.f / DM) - mu * mu + 1e-5f);
  const float4 g1v = ((const float4*)g1)[t];
  const float4 b1v = ((const float4*)b1)[t];
  float xn[4];
  xn[0] = (xv.x - mu) * rs * g1v.x + b1v.x;
  xn[1] = (xv.y - mu) * rs * g1v.y + b1v.y;
  xn[2] = (xv.z - mu) * rs * g1v.z + b1v.z;
  xn[3] = (xv.w - mu) * rs * g1v.w + b1v.w;
  float s2 = xn[0] + xn[1] + xn[2] + xn[3];
  float sq2 = xn[0] * xn[0] + xn[1] * xn[1] + xn[2] * xn[2] + xn[3] * xn[3];
  blockReduce2(s2, sq2, sred);
  const float mu2 = s2 * (1.f / DM);
  const float rs2 = rsqrtf(sq2 * (1.f / DM) - mu2 * mu2 + 1e-5f);
  const float4 g2v = ((const float4*)g2)[t];
  const float4 b2v = ((const float4*)b2)[t];
  u16x4 o;
  o[0] = f2b((xn[0] - mu2) * rs2 * g2v.x + b2v.x);
  o[1] = f2b((xn[1] - mu2) * rs2 * g2v.y + b2v.y);
  o[2] = f2b((xn[2] - mu2) * rs2 * g2v.z + b2v.z);
  o[3] = f2b((xn[3] - mu2) * rs2 * g2v.w + b2v.w);
  *(u16x4*)(out + row * DM + t * 4) = o;
}

// single LN, f32 in, bf16 out
__global__ __launch_bounds__(256)
void ln_kernel(const float* __restrict__ x, const float* __restrict__ g,
               const float* __restrict__ b, u16* __restrict__ out)
{
  __shared__ float sred[8];
  const long row = blockIdx.x;
  const int t = threadIdx.x;
  const float4 xv = ((const float4*)(x + row * DM))[t];
  float s = xv.x + xv.y + xv.z + xv.w;
  float sq = xv.x * xv.x + xv.y * xv.y + xv.z * xv.z + xv.w * xv.w;
  blockReduce2(s, sq, sred);
  const float mu = s * (1.f / DM);
  const float rs = rsqrtf(sq * (1.f / DM) - mu * mu + 1e-5f);
  const float4 gv = ((const float4*)g)[t];
  const float4 bv = ((const float4*)b)[t];
  u16x4 o;
  o[0] = f2b((xv.x - mu) * rs * gv.x + bv.x);
  o[1] = f2b((xv.y - mu) * rs * gv.y + bv.y);
  o[2] = f2b((xv.z - mu) * rs * gv.z + bv.z);
  o[3] = f2b((xv.w - mu) * rs * gv.w + bv.w);
  *(u16x4*)(out + row * DM + t * 4) = o;
}

// ---------------- depthwise conv (k=3, pad 1 along L) + silu, bf16->bf16 ----------------
__global__ __launch_bounds__(256)
void conv_silu_kernel(const u16* __restrict__ x1, const float* __restrict__ w,
                      u16* __restrict__ xc)
{
  const long idx = (long)blockIdx.x * 256 + threadIdx.x;  // NTOK*DM total
  const int d = (int)(idx & (DM - 1));
  const long m = idx >> 10;
  const int l = (int)(m & (SEQ - 1));
  const float c = b2f(x1[idx]);
  const float lf = (l > 0) ? b2f(x1[idx - DM]) : 0.f;
  const float rt = (l < SEQ - 1) ? b2f(x1[idx + DM]) : 0.f;
  const float a = lf * w[d * 3 + 0] + c * w[d * 3 + 1] + rt * w[d * 3 + 2];
  const float sv = a / (1.f + __expf(-a));
  xc[idx] = f2b(sv);
}

// ---------------- GEMM: C = A(MxK, bf16) * BT(NxK, bf16)^T, epilogue variants ----------------
// MODE 0: bf16 out = acc + bias
// MODE 1: bf16 out = silu(acc + bias)
// MODE 2: bf16 out = gelu_exact(acc + bias)
// MODE 3: f32  out = acc + bias + resid
// MODE 4: dtBC special: N=1152, f32 out stride 1152; col<1024 softplus(+dt_b);
//         col<1040 +Bp_b; col<1056 +Cp_b; col>=1056 skipped
template <int MODE>
__global__ __launch_bounds__(256)
void gemm_bt(const u16* __restrict__ A, const u16* __restrict__ BT,
             const float* __restrict__ bias, const float* __restrict__ bias2,
             const float* __restrict__ bias3, const float* __restrict__ resid,
             void* __restrict__ outp, int K, int ldOut)
{
  __shared__ u16 lds_a[128 * 32];
  __shared__ u16 lds_b[128 * 32];
  const int t = threadIdx.x;
  const int lane = t & 63;
  const int wid = t >> 6;
  const int wr = wid >> 1, wc = wid & 1;
  const long brow = (long)blockIdx.y * 128;
  const long bcol = (long)blockIdx.x * 128;

  f32x4 acc[4][4] = {};

  const u16* aPtr = A + (brow + (t >> 2)) * (long)K + (t & 3) * 8;
  const u16* bPtr = BT + (bcol + (t >> 2)) * (long)K + (t & 3) * 8;
  u16* la = &lds_a[t * 8];
  u16* lb = &lds_b[t * 8];
  const long rowStep = 64L * K;

  const int nk = K >> 5;
  for (int kt = 0; kt < nk; ++kt) {
    const int k0 = kt << 5;
    gload16(aPtr + k0, la);
    gload16(aPtr + rowStep + k0, la + 2048);
    gload16(bPtr + k0, lb);
    gload16(bPtr + rowStep + k0, lb + 2048);
    __syncthreads();
    short8 af[4], bf[4];
    const int arow = wr * 64 + (lane & 15);
    const int br2 = wc * 64 + (lane & 15);
    const int koff = (lane >> 4) * 8;
#pragma unroll
    for (int m = 0; m < 4; ++m)
      af[m] = *(const short8*)&lds_a[(arow + m * 16) * 32 + koff];
#pragma unroll
    for (int n = 0; n < 4; ++n)
      bf[n] = *(const short8*)&lds_b[(br2 + n * 16) * 32 + koff];
#pragma unroll
    for (int m = 0; m < 4; ++m)
#pragma unroll
      for (int n = 0; n < 4; ++n)
        acc[m][n] = __builtin_amdgcn_mfma_f32_16x16x32_bf16(af[m], bf[n], acc[m][n], 0, 0, 0);
    __syncthreads();
  }

  const int cc = lane & 15;
  const int r0 = (lane >> 4) * 4;
#pragma unroll
  for (int m = 0; m < 4; ++m) {
#pragma unroll
    for (int n = 0; n < 4; ++n) {
      const long col = bcol + wc * 64 + n * 16 + cc;
#pragma unroll
      for (int r = 0; r < 4; ++r) {
        const long row = brow + wr * 64 + m * 16 + r0 + r;
        float val = acc[m][n][r];
        if constexpr (MODE == 4) {
          if (col < 1024) {
            val += bias[col];
            val = (val > 20.f) ? val : log1pf(__expf(val));
            ((float*)outp)[row * 1152 + col] = val;
          } else if (col < 1040) {
            ((float*)outp)[row * 1152 + col] = val + bias2[col - 1024];
          } else if (col < 1056) {
            ((float*)outp)[row * 1152 + col] = val + bias3[col - 1040];
          }
        } else {
          val += bias[col];
          if constexpr (MODE == 1) val = val / (1.f + __expf(-val));
          if constexpr (MODE == 2) val = 0.5f * val * (1.f + erff(val * 0.70710678118f));
          if constexpr (MODE == 3) {
            ((float*)outp)[row * ldOut + col] = val + resid[row * ldOut + col];
          } else {
            ((u16*)outp)[row * ldOut + col] = f2b(val);
          }
        }
      }
    }
  }
}

// ---------------- selective-scan (fused with y*v), 4 states/thread ----------------
// grid: 64 blocks = b(4) x dblk(16, 64 d each); block 256 = 64 d x 4 n-quarters
__global__ __launch_bounds__(256)
void scan_kernel(const u16* __restrict__ xc, const float* __restrict__ dtbc,
                 const u16* __restrict__ vg, const float* __restrict__ A_log,
                 const float* __restrict__ D_p, u16* __restrict__ yv)
{
  const int b = blockIdx.x >> 4;
  const int dBase = (blockIdx.x & 15) * 64;
  const int t = threadIdx.x;
  const int dl = t >> 2;
  const int q = t & 3;
  const int d = dBase + dl;

  __shared__ float s_bc[32][32];
  __shared__ float s_dt[32][64];
  __shared__ u16 s_x[32][64];
  __shared__ u16 s_v[32][64];
  __shared__ u16 s_y[32][64];

  float Areg[4];
#pragma unroll
  for (int j = 0; j < 4; ++j) Areg[j] = -__expf(A_log[d * 16 + q * 4 + j]);
  const float Dp = D_p[d];
  float h[4] = {0.f, 0.f, 0.f, 0.f};

  const long mBase = (long)b * SEQ;

  for (int c0 = 0; c0 < SEQ; c0 += 32) {
#pragma unroll
    for (int i = 0; i < 4; ++i) {
      int idx = i * 256 + t;
      int s = idx >> 5, j = idx & 31;
      s_bc[s][j] = dtbc[(mBase + c0 + s) * 1152 + 1024 + j];
    }
#pragma unroll
    for (int i = 0; i < 8; ++i) {
      int idx = i * 256 + t;
      int s = idx >> 6, j = idx & 63;
      long m = mBase + c0 + s;
      s_dt[s][j] = dtbc[m * 1152 + dBase + j];
      s_x[s][j] = xc[m * DM + dBase + j];
      s_v[s][j] = vg[m * DM + dBase + j];
    }
    __syncthreads();
#pragma unroll 4
    for (int s = 0; s < 32; ++s) {
      const float dt = s_dt[s][dl];
      const float xt = b2f(s_x[s][dl]);
      const float p = dt * xt;
      float y = 0.f;
#pragma unroll
      for (int j = 0; j < 4; ++j) {
        const float dA = __expf(dt * Areg[j]);
        h[j] = dA * h[j] + p * s_bc[s][q * 4 + j];
        y = fmaf(h[j], s_bc[s][16 + q * 4 + j], y);
      }
      y += __shfl_xor(y, 1);
      y += __shfl_xor(y, 2);
      if (q == 0) s_y[s][dl] = f2b((y + Dp * xt) * b2f(s_v[s][dl]));
    }
    __syncthreads();
#pragma unroll
    for (int i = 0; i < 8; ++i) {
      int idx = i * 256 + t;
      int s = idx >> 6, j = idx & 63;
      yv[(mBase + c0 + s) * DM + dBase + j] = s_y[s][j];
    }
    __syncthreads();
  }
}

extern "C" void kernel_launch(void* const* d_in, const int* in_sizes, int n_in,
                              void* d_out, int out_size, void* d_ws, size_t ws_size,
                              hipStream_t stream)
{
  (void)in_sizes; (void)n_in; (void)out_size; (void)ws_size;
  const float* x      = (const float*)d_in[0];
  const float* ln1_g  = (const float*)d_in[1];
  const float* ln1_b  = (const float*)d_in[2];
  const float* ln_g   = (const float*)d_in[3];
  const float* ln_b   = (const float*)d_in[4];
  const float* w1_w   = (const float*)d_in[5];
  const float* w1_b   = (const float*)d_in[6];
  const float* v1_w   = (const float*)d_in[7];
  const float* v1_b   = (const float*)d_in[8];
  const float* w2_w   = (const float*)d_in[9];
  const float* w2_b   = (const float*)d_in[10];
  const float* conv_w = (const float*)d_in[11];
  const float* dt_w   = (const float*)d_in[12];
  const float* dt_b   = (const float*)d_in[13];
  const float* Bp_w   = (const float*)d_in[14];
  const float* Bp_b   = (const float*)d_in[15];
  const float* Cp_w   = (const float*)d_in[16];
  const float* Cp_b   = (const float*)d_in[17];
  const float* A_log  = (const float*)d_in[18];
  const float* D_p    = (const float*)d_in[19];
  const float* ln2_g  = (const float*)d_in[20];
  const float* ln2_b  = (const float*)d_in[21];
  const float* ff1_w  = (const float*)d_in[22];
  const float* ff1_b  = (const float*)d_in[23];
  const float* ff2_w  = (const float*)d_in[24];
  const float* ff2_b  = (const float*)d_in[25];

  char* ws = (char*)d_ws;
  size_t cur = 0;
  auto alloc = [&](size_t bytes) -> void* {
    void* p = ws + cur;
    cur = (cur + bytes + 255) & ~(size_t)255;
    return p;
  };

  u16* w1T   = (u16*)alloc((size_t)1024 * 1024 * 2);
  u16* v1T   = (u16*)alloc((size_t)1024 * 1024 * 2);
  u16* w2T   = (u16*)alloc((size_t)1024 * 1024 * 2);
  u16* wcatT = (u16*)alloc((size_t)1152 * 1024 * 2);
  u16* ff1T  = (u16*)alloc((size_t)3072 * 1024 * 2);
  u16* ff2T  = (u16*)alloc((size_t)1024 * 3072 * 2);
  u16* xm    = (u16*)alloc((size_t)NTOK * DM * 2);
  u16* x1b   = (u16*)alloc((size_t)NTOK * DM * 2);
  u16* vb    = (u16*)alloc((size_t)NTOK * DM * 2);
  u16* xcb   = (u16*)alloc((size_t)NTOK * DM * 2);       // also start of h region
  float* dtbc = (float*)alloc((size_t)NTOK * 1152 * 4);
  float* x2  = (float*)alloc((size_t)NTOK * DM * 4);
  u16* yvb  = xm;        // reuse: xm dead after v GEMM
  u16* xn2  = x1b;       // reuse: x1 dead after conv
  u16* hb   = xcb;       // reuse: xc+dtbc dead after scan (16.7+37.7 MB >= 50.3 MB)

  const dim3 tb32(32, 8);
  // weight prep
  wtrans<<<dim3(32, 32), tb32, 0, stream>>>(w1_w, w1T, 1024, 1024, 0, 1024);
  wtrans<<<dim3(32, 32), tb32, 0, stream>>>(v1_w, v1T, 1024, 1024, 0, 1024);
  wtrans<<<dim3(32, 32), tb32, 0, stream>>>(w2_w, w2T, 1024, 1024, 0, 1024);
  wtrans<<<dim3(32, 32), tb32, 0, stream>>>(dt_w, wcatT, 1024, 1024, 0, 1024);
  small_trans<<<64, 256, 0, stream>>>(Bp_w, Cp_w, wcatT);
  hipMemsetAsync(wcatT + (size_t)1056 * 1024, 0, (size_t)96 * 1024 * 2, stream);
  wtrans<<<dim3(96, 32), tb32, 0, stream>>>(ff1_w, ff1T, 1024, 3072, 0, 1024);
  wtrans<<<dim3(32, 96), tb32, 0, stream>>>(ff2_w, ff2T, 3072, 1024, 0, 3072);

  // LN1 -> LN2 -> xm (bf16)
  ln_ln_kernel<<<NTOK, 256, 0, stream>>>(x, ln1_g, ln1_b, ln_g, ln_b, xm);

  // x1 = xm @ w1 + b (bf16); v = silu(xm @ v1 + b)
  gemm_bt<0><<<dim3(8, 64), 256, 0, stream>>>(xm, w1T, w1_b, nullptr, nullptr, nullptr, x1b, 1024, 1024);
  gemm_bt<1><<<dim3(8, 64), 256, 0, stream>>>(xm, v1T, v1_b, nullptr, nullptr, nullptr, vb, 1024, 1024);

  // xc = silu(depthwise_conv(x1))
  conv_silu_kernel<<<(NTOK * DM) / 256, 256, 0, stream>>>(x1b, conv_w, xcb);

  // dtBC = [softplus(xc@dt_w+dt_b) | xc@Bp_w+Bp_b | xc@Cp_w+Cp_b | pad]  (f32, ld 1152)
  gemm_bt<4><<<dim3(9, 64), 256, 0, stream>>>(xcb, wcatT, dt_b, Bp_b, Cp_b, nullptr, dtbc, 1024, 1152);

  // selective scan fused with y*v -> yv (bf16)
  scan_kernel<<<64, 256, 0, stream>>>(xcb, dtbc, vb, A_log, D_p, yvb);

  // x2 = yv @ w2 + b + x (f32)
  gemm_bt<3><<<dim3(8, 64), 256, 0, stream>>>(yvb, w2T, w2_b, nullptr, nullptr, x, x2, 1024, 1024);

  // xn2 = LN(x2) (bf16)
  ln_kernel<<<NTOK, 256, 0, stream>>>(x2, ln2_g, ln2_b, xn2);

  // h = gelu(xn2 @ ff1 + b) (bf16, ld 3072)
  gemm_bt<2><<<dim3(24, 64), 256, 0, stream>>>(xn2, ff1T, ff1_b, nullptr, nullptr, nullptr, hb, 1024, 3072);

  // out = h @ ff2 + b + x2 (f32)
  gemm_bt<3><<<dim3(8, 64), 256, 0, stream>>>(hb, ff2T, ff2_b, nullptr, nullptr, x2, d_out, 3072, 1024);
}

// Round 2
// 517.978 us; speedup vs baseline: 2.4741x; 2.4741x over previous
//
#include <hip/hip_runtime.h>

typedef unsigned short u16;
typedef __attribute__((ext_vector_type(8))) short short8;
typedef __attribute__((ext_vector_type(4))) float f32x4;
typedef __attribute__((ext_vector_type(4))) unsigned short u16x4;

#define SEQ 2048
#define DM 1024
#define NTOK 8192  // B*L
#define CH 64      // scan chunk length
#define NCH 32     // SEQ / CH

__device__ __forceinline__ float b2f(u16 u) {
  union { float f; unsigned int i; } x; x.i = ((unsigned int)u) << 16; return x.f;
}
__device__ __forceinline__ u16 f2b(float f) {
  union { float f; unsigned int i; } x; x.f = f;
  unsigned int i = x.i;
  unsigned int r = (i + 0x7FFFu + ((i >> 16) & 1u)) >> 16;
  return (u16)r;
}

__device__ __forceinline__ void gload16(const u16* g, u16* l) {
  __builtin_amdgcn_global_load_lds(
      (const __attribute__((address_space(1))) void*)g,
      (__attribute__((address_space(3))) void*)l, 16, 0, 0);
}

// ---------------- weight transpose f32 (K x N) -> bf16 (N x K) ----------------
__global__ __launch_bounds__(256)
void wtrans(const float* __restrict__ in, u16* __restrict__ out,
            int K, int N, int rowOff, int ldOut)
{
  __shared__ float tile[32][33];
  const int n0 = blockIdx.x * 32;
  const int k0 = blockIdx.y * 32;
  const int tx = threadIdx.x, ty = threadIdx.y;
#pragma unroll
  for (int i = 0; i < 32; i += 8) {
    int k = k0 + ty + i, n = n0 + tx;
    tile[ty + i][tx] = (k < K && n < N) ? in[(long)k * N + n] : 0.f;
  }
  __syncthreads();
#pragma unroll
  for (int i = 0; i < 32; i += 8) {
    int n = n0 + ty + i, k = k0 + tx;
    if (n < N && k < K) out[(long)(rowOff + n) * ldOut + k] = f2b(tile[tx][ty + i]);
  }
}

// Bp_w/Cp_w (1024x16) -> rows [1024..1055] of WcatT (ld 1024)
__global__ __launch_bounds__(256)
void small_trans(const float* __restrict__ Bp, const float* __restrict__ Cp,
                 u16* __restrict__ wcatT)
{
  int t = blockIdx.x * 256 + threadIdx.x;  // 16384 threads
  int n = t >> 10, k = t & 1023;
  wcatT[(long)(1024 + n) * 1024 + k] = f2b(Bp[(long)k * 16 + n]);
  wcatT[(long)(1040 + n) * 1024 + k] = f2b(Cp[(long)k * 16 + n]);
}

// ---------------- LayerNorm helpers ----------------
__device__ __forceinline__ void blockReduce2(float& a, float& b, float* s)
{
#pragma unroll
  for (int off = 32; off > 0; off >>= 1) {
    a += __shfl_xor(a, off);
    b += __shfl_xor(b, off);
  }
  const int lane = threadIdx.x & 63, wid = threadIdx.x >> 6;
  __syncthreads();
  if (lane == 0) { s[wid] = a; s[4 + wid] = b; }
  __syncthreads();
  a = s[0] + s[1] + s[2] + s[3];
  b = s[4] + s[5] + s[6] + s[7];
}

// fused LN1 -> LN2, f32 in, bf16 out (row length 1024, 256 thr x 4 elems)
__global__ __launch_bounds__(256)
void ln_ln_kernel(const float* __restrict__ x, const float* __restrict__ g1,
                  const float* __restrict__ b1, const float* __restrict__ g2,
                  const float* __restrict__ b2, u16* __restrict__ out)
{
  __shared__ float sred[8];
  const long row = blockIdx.x;
  const int t = threadIdx.x;
  const float4 xv = ((const float4*)(x + row * DM))[t];
  float s = xv.x + xv.y + xv.z + xv.w;
  float sq = xv.x * xv.x + xv.y * xv.y + xv.z * xv.z + xv.w * xv.w;
  blockReduce2(s, sq, sred);
  const float mu = s * (1.f / DM);
  const float rs = rsqrtf(sq * (1.f / DM) - mu * mu + 1e-5f);
  const float4 g1v = ((const float4*)g1)[t];
  const float4 b1v = ((const float4*)b1)[t];
  float xn[4];
  xn[0] = (xv.x - mu) * rs * g1v.x + b1v.x;
  xn[1] = (xv.y - mu) * rs * g1v.y + b1v.y;
  xn[2] = (xv.z - mu) * rs * g1v.z + b1v.z;
  xn[3] = (xv.w - mu) * rs * g1v.w + b1v.w;
  float s2 = xn[0] + xn[1] + xn[2] + xn[3];
  float sq2 = xn[0] * xn[0] + xn[1] * xn[1] + xn[2] * xn[2] + xn[3] * xn[3];
  blockReduce2(s2, sq2, sred);
  const float mu2 = s2 * (1.f / DM);
  const float rs2 = rsqrtf(sq2 * (1.f / DM) - mu2 * mu2 + 1e-5f);
  const float4 g2v = ((const float4*)g2)[t];
  const float4 b2v = ((const float4*)b2)[t];
  u16x4 o;
  o[0] = f2b((xn[0] - mu2) * rs2 * g2v.x + b2v.x);
  o[1] = f2b((xn[1] - mu2) * rs2 * g2v.y + b2v.y);
  o[2] = f2b((xn[2] - mu2) * rs2 * g2v.z + b2v.z);
  o[3] = f2b((xn[3] - mu2) * rs2 * g2v.w + b2v.w);
  *(u16x4*)(out + row * DM + t * 4) = o;
}

// single LN, f32 in, bf16 out
__global__ __launch_bounds__(256)
void ln_kernel(const float* __restrict__ x, const float* __restrict__ g,
               const float* __restrict__ b, u16* __restrict__ out)
{
  __shared__ float sred[8];
  const long row = blockIdx.x;
  const int t = threadIdx.x;
  const float4 xv = ((const float4*)(x + row * DM))[t];
  float s = xv.x + xv.y + xv.z + xv.w;
  float sq = xv.x * xv.x + xv.y * xv.y + xv.z * xv.z + xv.w * xv.w;
  blockReduce2(s, sq, sred);
  const float mu = s * (1.f / DM);
  const float rs = rsqrtf(sq * (1.f / DM) - mu * mu + 1e-5f);
  const float4 gv = ((const float4*)g)[t];
  const float4 bv = ((const float4*)b)[t];
  u16x4 o;
  o[0] = f2b((xv.x - mu) * rs * gv.x + bv.x);
  o[1] = f2b((xv.y - mu) * rs * gv.y + bv.y);
  o[2] = f2b((xv.z - mu) * rs * gv.z + bv.z);
  o[3] = f2b((xv.w - mu) * rs * gv.w + bv.w);
  *(u16x4*)(out + row * DM + t * 4) = o;
}

// ---------------- depthwise conv (k=3, pad 1 along L) + silu, bf16->bf16 ----------------
__global__ __launch_bounds__(256)
void conv_silu_kernel(const u16* __restrict__ x1, const float* __restrict__ w,
                      u16* __restrict__ xc)
{
  const long idx = (long)blockIdx.x * 256 + threadIdx.x;  // NTOK*DM total
  const int d = (int)(idx & (DM - 1));
  const long m = idx >> 10;
  const int l = (int)(m & (SEQ - 1));
  const float c = b2f(x1[idx]);
  const float lf = (l > 0) ? b2f(x1[idx - DM]) : 0.f;
  const float rt = (l < SEQ - 1) ? b2f(x1[idx + DM]) : 0.f;
  const float a = lf * w[d * 3 + 0] + c * w[d * 3 + 1] + rt * w[d * 3 + 2];
  const float sv = a / (1.f + __expf(-a));
  xc[idx] = f2b(sv);
}

// ---------------- GEMM: C = A(MxK, bf16) * BT(NxK, bf16)^T, epilogue variants ----------------
template <int MODE>
__global__ __launch_bounds__(256)
void gemm_bt(const u16* __restrict__ A, const u16* __restrict__ BT,
             const float* __restrict__ bias, const float* __restrict__ bias2,
             const float* __restrict__ bias3, const float* __restrict__ resid,
             void* __restrict__ outp, int K, int ldOut)
{
  __shared__ u16 lds_a[128 * 32];
  __shared__ u16 lds_b[128 * 32];
  const int t = threadIdx.x;
  const int lane = t & 63;
  const int wid = t >> 6;
  const int wr = wid >> 1, wc = wid & 1;
  const long brow = (long)blockIdx.y * 128;
  const long bcol = (long)blockIdx.x * 128;

  f32x4 acc[4][4] = {};

  const u16* aPtr = A + (brow + (t >> 2)) * (long)K + (t & 3) * 8;
  const u16* bPtr = BT + (bcol + (t >> 2)) * (long)K + (t & 3) * 8;
  u16* la = &lds_a[t * 8];
  u16* lb = &lds_b[t * 8];
  const long rowStep = 64L * K;

  const int nk = K >> 5;
  for (int kt = 0; kt < nk; ++kt) {
    const int k0 = kt << 5;
    gload16(aPtr + k0, la);
    gload16(aPtr + rowStep + k0, la + 2048);
    gload16(bPtr + k0, lb);
    gload16(bPtr + rowStep + k0, lb + 2048);
    __syncthreads();
    short8 af[4], bf[4];
    const int arow = wr * 64 + (lane & 15);
    const int br2 = wc * 64 + (lane & 15);
    const int koff = (lane >> 4) * 8;
#pragma unroll
    for (int m = 0; m < 4; ++m)
      af[m] = *(const short8*)&lds_a[(arow + m * 16) * 32 + koff];
#pragma unroll
    for (int n = 0; n < 4; ++n)
      bf[n] = *(const short8*)&lds_b[(br2 + n * 16) * 32 + koff];
#pragma unroll
    for (int m = 0; m < 4; ++m)
#pragma unroll
      for (int n = 0; n < 4; ++n)
        acc[m][n] = __builtin_amdgcn_mfma_f32_16x16x32_bf16(af[m], bf[n], acc[m][n], 0, 0, 0);
    __syncthreads();
  }

  const int cc = lane & 15;
  const int r0 = (lane >> 4) * 4;
#pragma unroll
  for (int m = 0; m < 4; ++m) {
#pragma unroll
    for (int n = 0; n < 4; ++n) {
      const long col = bcol + wc * 64 + n * 16 + cc;
#pragma unroll
      for (int r = 0; r < 4; ++r) {
        const long row = brow + wr * 64 + m * 16 + r0 + r;
        float val = acc[m][n][r];
        if constexpr (MODE == 4) {
          if (col < 1024) {
            val += bias[col];
            val = (val > 20.f) ? val : log1pf(__expf(val));
            ((float*)outp)[row * 1152 + col] = val;
          } else if (col < 1040) {
            ((float*)outp)[row * 1152 + col] = val + bias2[col - 1024];
          } else if (col < 1056) {
            ((float*)outp)[row * 1152 + col] = val + bias3[col - 1040];
          }
        } else {
          val += bias[col];
          if constexpr (MODE == 1) val = val / (1.f + __expf(-val));
          if constexpr (MODE == 2) val = 0.5f * val * (1.f + erff(val * 0.70710678118f));
          if constexpr (MODE == 3) {
            ((float*)outp)[row * ldOut + col] = val + resid[row * ldOut + col];
          } else {
            ((u16*)outp)[row * ldOut + col] = f2b(val);
          }
        }
      }
    }
  }
}

// ---------------- chunked selective scan ----------------
// pass 1: per-chunk local scan (h0 = 0); outputs h_out per chunk + sum(dt) per chunk
// grid: 2048 blocks = b(4) x ch(32) x dblk(16); block 256 = 64 d x 4 q
__global__ __launch_bounds__(256)
void scan_pass1(const u16* __restrict__ xc, const float* __restrict__ dtbc,
                const float* __restrict__ A_log, float* __restrict__ hloc,
                float* __restrict__ sdt)
{
  const int bx = blockIdx.x;
  const int b = bx >> 9;
  const int ch = (bx >> 4) & 31;
  const int dBase = (bx & 15) * 64;
  const int t = threadIdx.x;
  const int dl = t >> 2;
  const int q = t & 3;
  const int d = dBase + dl;

  __shared__ float s_b[32][16];
  __shared__ float s_dt[32][64];
  __shared__ u16 s_x[32][64];

  float Areg[4];
#pragma unroll
  for (int j = 0; j < 4; ++j) Areg[j] = -__expf(A_log[d * 16 + q * 4 + j]);
  float h[4] = {0.f, 0.f, 0.f, 0.f};
  float sAcc = 0.f;
  const long mBase = (long)b * SEQ + ch * CH;

  for (int c0 = 0; c0 < CH; c0 += 32) {
#pragma unroll
    for (int i = 0; i < 2; ++i) {
      int idx = i * 256 + t;
      int s = idx >> 4, j = idx & 15;
      s_b[s][j] = dtbc[(mBase + c0 + s) * 1152 + 1024 + j];
    }
#pragma unroll
    for (int i = 0; i < 8; ++i) {
      int idx = i * 256 + t;
      int s = idx >> 6, j = idx & 63;
      long m = mBase + c0 + s;
      s_dt[s][j] = dtbc[m * 1152 + dBase + j];
      s_x[s][j] = xc[m * DM + dBase + j];
    }
    __syncthreads();
#pragma unroll 4
    for (int s = 0; s < 32; ++s) {
      const float dt = s_dt[s][dl];
      const float p = dt * b2f(s_x[s][dl]);
      sAcc += dt;
#pragma unroll
      for (int j = 0; j < 4; ++j)
        h[j] = __expf(dt * Areg[j]) * h[j] + p * s_b[s][q * 4 + j];
    }
    __syncthreads();
  }
  const long base = (((long)b * NCH + ch) * 1024 + d) * 16 + q * 4;
  float4 hv; hv.x = h[0]; hv.y = h[1]; hv.z = h[2]; hv.w = h[3];
  *(float4*)&hloc[base] = hv;
  if (q == 0) sdt[((long)b * NCH + ch) * 1024 + d] = sAcc;
}

// pass 2: sequential combine over chunks: h_in[c+1] = exp(A*sdt[c])*h_in[c] + hloc[c]
// 65536 threads = (b, d, n)
__global__ __launch_bounds__(256)
void scan_pass2(const float* __restrict__ A_log, const float* __restrict__ sdt,
                const float* __restrict__ hloc, float* __restrict__ hin)
{
  const int tid = blockIdx.x * 256 + threadIdx.x;
  const int b = tid >> 14;
  const int dn = tid & 16383;
  const int d = dn >> 4;
  const float A = -__expf(A_log[dn]);
  float h = 0.f;
  for (int c = 0; c < NCH; ++c) {
    const long idx = (((long)b * NCH + c) << 14) + dn;
    hin[idx] = h;
    h = __expf(A * sdt[((long)b * NCH + c) * 1024 + d]) * h + hloc[idx];
  }
}

// pass 3: re-run recurrence from correct h_in, compute y and fuse y*v
__global__ __launch_bounds__(256)
void scan_pass3(const u16* __restrict__ xc, const float* __restrict__ dtbc,
                const u16* __restrict__ vg, const float* __restrict__ A_log,
                const float* __restrict__ D_p, const float* __restrict__ hin,
                u16* __restrict__ yv)
{
  const int bx = blockIdx.x;
  const int b = bx >> 9;
  const int ch = (bx >> 4) & 31;
  const int dBase = (bx & 15) * 64;
  const int t = threadIdx.x;
  const int dl = t >> 2;
  const int q = t & 3;
  const int d = dBase + dl;

  __shared__ float s_bc[32][32];
  __shared__ float s_dt[32][64];
  __shared__ u16 s_x[32][64];
  __shared__ u16 s_v[32][64];
  __shared__ u16 s_y[32][64];

  float Areg[4];
#pragma unroll
  for (int j = 0; j < 4; ++j) Areg[j] = -__expf(A_log[d * 16 + q * 4 + j]);
  const float Dp = D_p[d];
  const float4 hv = *(const float4*)&hin[(((long)b * NCH + ch) * 1024 + d) * 16 + q * 4];
  float h[4] = {hv.x, hv.y, hv.z, hv.w};

  const long mBase = (long)b * SEQ + ch * CH;

  for (int c0 = 0; c0 < CH; c0 += 32) {
#pragma unroll
    for (int i = 0; i < 4; ++i) {
      int idx = i * 256 + t;
      int s = idx >> 5, j = idx & 31;
      s_bc[s][j] = dtbc[(mBase + c0 + s) * 1152 + 1024 + j];
    }
#pragma unroll
    for (int i = 0; i < 8; ++i) {
      int idx = i * 256 + t;
      int s = idx >> 6, j = idx & 63;
      long m = mBase + c0 + s;
      s_dt[s][j] = dtbc[m * 1152 + dBase + j];
      s_x[s][j] = xc[m * DM + dBase + j];
      s_v[s][j] = vg[m * DM + dBase + j];
    }
    __syncthreads();
#pragma unroll 4
    for (int s = 0; s < 32; ++s) {
      const float dt = s_dt[s][dl];
      const float xt = b2f(s_x[s][dl]);
      const float p = dt * xt;
      float y = 0.f;
#pragma unroll
      for (int j = 0; j < 4; ++j) {
        const float dA = __expf(dt * Areg[j]);
        h[j] = dA * h[j] + p * s_bc[s][q * 4 + j];
        y = fmaf(h[j], s_bc[s][16 + q * 4 + j], y);
      }
      y += __shfl_xor(y, 1);
      y += __shfl_xor(y, 2);
      if (q == 0) s_y[s][dl] = f2b((y + Dp * xt) * b2f(s_v[s][dl]));
    }
    __syncthreads();
#pragma unroll
    for (int i = 0; i < 8; ++i) {
      int idx = i * 256 + t;
      int s = idx >> 6, j = idx & 63;
      yv[(mBase + c0 + s) * DM + dBase + j] = s_y[s][j];
    }
    __syncthreads();
  }
}

extern "C" void kernel_launch(void* const* d_in, const int* in_sizes, int n_in,
                              void* d_out, int out_size, void* d_ws, size_t ws_size,
                              hipStream_t stream)
{
  (void)in_sizes; (void)n_in; (void)out_size; (void)ws_size;
  const float* x      = (const float*)d_in[0];
  const float* ln1_g  = (const float*)d_in[1];
  const float* ln1_b  = (const float*)d_in[2];
  const float* ln_g   = (const float*)d_in[3];
  const float* ln_b   = (const float*)d_in[4];
  const float* w1_w   = (const float*)d_in[5];
  const float* w1_b   = (const float*)d_in[6];
  const float* v1_w   = (const float*)d_in[7];
  const float* v1_b   = (const float*)d_in[8];
  const float* w2_w   = (const float*)d_in[9];
  const float* w2_b   = (const float*)d_in[10];
  const float* conv_w = (const float*)d_in[11];
  const float* dt_w   = (const float*)d_in[12];
  const float* dt_b   = (const float*)d_in[13];
  const float* Bp_w   = (const float*)d_in[14];
  const float* Bp_b   = (const float*)d_in[15];
  const float* Cp_w   = (const float*)d_in[16];
  const float* Cp_b   = (const float*)d_in[17];
  const float* A_log  = (const float*)d_in[18];
  const float* D_p    = (const float*)d_in[19];
  const float* ln2_g  = (const float*)d_in[20];
  const float* ln2_b  = (const float*)d_in[21];
  const float* ff1_w  = (const float*)d_in[22];
  const float* ff1_b  = (const float*)d_in[23];
  const float* ff2_w  = (const float*)d_in[24];
  const float* ff2_b  = (const float*)d_in[25];

  char* ws = (char*)d_ws;
  size_t cur = 0;
  auto alloc = [&](size_t bytes) -> void* {
    void* p = ws + cur;
    cur = (cur + bytes + 255) & ~(size_t)255;
    return p;
  };

  u16* w1T   = (u16*)alloc((size_t)1024 * 1024 * 2);
  u16* v1T   = (u16*)alloc((size_t)1024 * 1024 * 2);
  u16* w2T   = (u16*)alloc((size_t)1024 * 1024 * 2);
  u16* wcatT = (u16*)alloc((size_t)1152 * 1024 * 2);
  u16* ff1T  = (u16*)alloc((size_t)3072 * 1024 * 2);
  u16* ff2T  = (u16*)alloc((size_t)1024 * 3072 * 2);
  u16* xm    = (u16*)alloc((size_t)NTOK * DM * 2);
  u16* x1b   = (u16*)alloc((size_t)NTOK * DM * 2);
  u16* vb    = (u16*)alloc((size_t)NTOK * DM * 2);
  u16* xcb   = (u16*)alloc((size_t)NTOK * DM * 2);       // also start of h region
  float* dtbc = (float*)alloc((size_t)NTOK * 1152 * 4);
  float* x2  = (float*)alloc((size_t)NTOK * DM * 4);
  float* hloc = (float*)alloc((size_t)4 * NCH * 1024 * 16 * 4);  // 8 MB
  float* hin  = (float*)alloc((size_t)4 * NCH * 1024 * 16 * 4);  // 8 MB
  float* sdtb = (float*)alloc((size_t)4 * NCH * 1024 * 4);       // 512 KB
  u16* yvb  = xm;        // reuse: xm dead after v GEMM
  u16* xn2  = x1b;       // reuse: x1 dead after conv
  u16* hb   = xcb;       // reuse: xc+dtbc dead after scan (16.7+37.7 MB >= 50.3 MB)

  const dim3 tb32(32, 8);
  // weight prep
  wtrans<<<dim3(32, 32), tb32, 0, stream>>>(w1_w, w1T, 1024, 1024, 0, 1024);
  wtrans<<<dim3(32, 32), tb32, 0, stream>>>(v1_w, v1T, 1024, 1024, 0, 1024);
  wtrans<<<dim3(32, 32), tb32, 0, stream>>>(w2_w, w2T, 1024, 1024, 0, 1024);
  wtrans<<<dim3(32, 32), tb32, 0, stream>>>(dt_w, wcatT, 1024, 1024, 0, 1024);
  small_trans<<<64, 256, 0, stream>>>(Bp_w, Cp_w, wcatT);
  hipMemsetAsync(wcatT + (size_t)1056 * 1024, 0, (size_t)96 * 1024 * 2, stream);
  wtrans<<<dim3(96, 32), tb32, 0, stream>>>(ff1_w, ff1T, 1024, 3072, 0, 1024);
  wtrans<<<dim3(32, 96), tb32, 0, stream>>>(ff2_w, ff2T, 3072, 1024, 0, 3072);

  // LN1 -> LN2 -> xm (bf16)
  ln_ln_kernel<<<NTOK, 256, 0, stream>>>(x, ln1_g, ln1_b, ln_g, ln_b, xm);

  // x1 = xm @ w1 + b (bf16); v = silu(xm @ v1 + b)
  gemm_bt<0><<<dim3(8, 64), 256, 0, stream>>>(xm, w1T, w1_b, nullptr, nullptr, nullptr, x1b, 1024, 1024);
  gemm_bt<1><<<dim3(8, 64), 256, 0, stream>>>(xm, v1T, v1_b, nullptr, nullptr, nullptr, vb, 1024, 1024);

  // xc = silu(depthwise_conv(x1))
  conv_silu_kernel<<<(NTOK * DM) / 256, 256, 0, stream>>>(x1b, conv_w, xcb);

  // dtBC = [softplus(xc@dt_w+dt_b) | xc@Bp_w+Bp_b | xc@Cp_w+Cp_b | pad]  (f32, ld 1152)
  gemm_bt<4><<<dim3(9, 64), 256, 0, stream>>>(xcb, wcatT, dt_b, Bp_b, Cp_b, nullptr, dtbc, 1024, 1152);

  // chunked selective scan fused with y*v -> yv (bf16)
  scan_pass1<<<2048, 256, 0, stream>>>(xcb, dtbc, A_log, hloc, sdtb);
  scan_pass2<<<256, 256, 0, stream>>>(A_log, sdtb, hloc, hin);
  scan_pass3<<<2048, 256, 0, stream>>>(xcb, dtbc, vb, A_log, D_p, hin, yvb);

  // x2 = yv @ w2 + b + x (f32)
  gemm_bt<3><<<dim3(8, 64), 256, 0, stream>>>(yvb, w2T, w2_b, nullptr, nullptr, x, x2, 1024, 1024);

  // xn2 = LN(x2) (bf16)
  ln_kernel<<<NTOK, 256, 0, stream>>>(x2, ln2_g, ln2_b, xn2);

  // h = gelu(xn2 @ ff1 + b) (bf16, ld 3072)
  gemm_bt<2><<<dim3(24, 64), 256, 0, stream>>>(xn2, ff1T, ff1_b, nullptr, nullptr, nullptr, hb, 1024, 3072);

  // out = h @ ff2 + b + x2 (f32)
  gemm_bt<3><<<dim3(8, 64), 256, 0, stream>>>(hb, ff2T, ff2_b, nullptr, nullptr, x2, d_out, 3072, 1024);
}

// Round 3
// 470.844 us; speedup vs baseline: 2.7217x; 1.1001x over previous
//
#include <hip/hip_runtime.h>

typedef unsigned short u16;
typedef __attribute__((ext_vector_type(8))) short short8;
typedef __attribute__((ext_vector_type(4))) float f32x4;
typedef __attribute__((ext_vector_type(4))) unsigned short u16x4;

#define SEQ 2048
#define DM 1024
#define NTOK 8192  // B*L
#define CH 64      // scan chunk length
#define NCH 32     // SEQ / CH

__device__ __forceinline__ float b2f(u16 u) {
  union { float f; unsigned int i; } x; x.i = ((unsigned int)u) << 16; return x.f;
}
__device__ __forceinline__ u16 f2b(float f) {
  union { float f; unsigned int i; } x; x.f = f;
  unsigned int i = x.i;
  unsigned int r = (i + 0x7FFFu + ((i >> 16) & 1u)) >> 16;
  return (u16)r;
}

__device__ __forceinline__ void gload16(const u16* g, u16* l) {
  __builtin_amdgcn_global_load_lds(
      (const __attribute__((address_space(1))) void*)g,
      (__attribute__((address_space(3))) void*)l, 16, 0, 0);
}

// ---------------- weight transpose f32 (K x N) -> bf16 (N x K) ----------------
__global__ __launch_bounds__(256)
void wtrans(const float* __restrict__ in, u16* __restrict__ out,
            int K, int N, int rowOff, int ldOut)
{
  __shared__ float tile[32][33];
  const int n0 = blockIdx.x * 32;
  const int k0 = blockIdx.y * 32;
  const int tx = threadIdx.x, ty = threadIdx.y;
#pragma unroll
  for (int i = 0; i < 32; i += 8) {
    int k = k0 + ty + i, n = n0 + tx;
    tile[ty + i][tx] = (k < K && n < N) ? in[(long)k * N + n] : 0.f;
  }
  __syncthreads();
#pragma unroll
  for (int i = 0; i < 32; i += 8) {
    int n = n0 + ty + i, k = k0 + tx;
    if (n < N && k < K) out[(long)(rowOff + n) * ldOut + k] = f2b(tile[tx][ty + i]);
  }
}

// Bp_w/Cp_w (1024x16) -> rows [1024..1055] of WcatT (ld 1024)
__global__ __launch_bounds__(256)
void small_trans(const float* __restrict__ Bp, const float* __restrict__ Cp,
                 u16* __restrict__ wcatT)
{
  int t = blockIdx.x * 256 + threadIdx.x;  // 16384 threads
  int n = t >> 10, k = t & 1023;
  wcatT[(long)(1024 + n) * 1024 + k] = f2b(Bp[(long)k * 16 + n]);
  wcatT[(long)(1040 + n) * 1024 + k] = f2b(Cp[(long)k * 16 + n]);
}

// ---------------- LayerNorm helpers ----------------
__device__ __forceinline__ void blockReduce2(float& a, float& b, float* s)
{
#pragma unroll
  for (int off = 32; off > 0; off >>= 1) {
    a += __shfl_xor(a, off);
    b += __shfl_xor(b, off);
  }
  const int lane = threadIdx.x & 63, wid = threadIdx.x >> 6;
  __syncthreads();
  if (lane == 0) { s[wid] = a; s[4 + wid] = b; }
  __syncthreads();
  a = s[0] + s[1] + s[2] + s[3];
  b = s[4] + s[5] + s[6] + s[7];
}

// fused LN1 -> LN2, f32 in, bf16 out (row length 1024, 256 thr x 4 elems)
__global__ __launch_bounds__(256)
void ln_ln_kernel(const float* __restrict__ x, const float* __restrict__ g1,
                  const float* __restrict__ b1, const float* __restrict__ g2,
                  const float* __restrict__ b2, u16* __restrict__ out)
{
  __shared__ float sred[8];
  const long row = blockIdx.x;
  const int t = threadIdx.x;
  const float4 xv = ((const float4*)(x + row * DM))[t];
  float s = xv.x + xv.y + xv.z + xv.w;
  float sq = xv.x * xv.x + xv.y * xv.y + xv.z * xv.z + xv.w * xv.w;
  blockReduce2(s, sq, sred);
  const float mu = s * (1.f / DM);
  const float rs = rsqrtf(sq * (1.f / DM) - mu * mu + 1e-5f);
  const float4 g1v = ((const float4*)g1)[t];
  const float4 b1v = ((const float4*)b1)[t];
  float xn[4];
  xn[0] = (xv.x - mu) * rs * g1v.x + b1v.x;
  xn[1] = (xv.y - mu) * rs * g1v.y + b1v.y;
  xn[2] = (xv.z - mu) * rs * g1v.z + b1v.z;
  xn[3] = (xv.w - mu) * rs * g1v.w + b1v.w;
  float s2 = xn[0] + xn[1] + xn[2] + xn[3];
  float sq2 = xn[0] * xn[0] + xn[1] * xn[1] + xn[2] * xn[2] + xn[3] * xn[3];
  blockReduce2(s2, sq2, sred);
  const float mu2 = s2 * (1.f / DM);
  const float rs2 = rsqrtf(sq2 * (1.f / DM) - mu2 * mu2 + 1e-5f);
  const float4 g2v = ((const float4*)g2)[t];
  const float4 b2v = ((const float4*)b2)[t];
  u16x4 o;
  o[0] = f2b((xn[0] - mu2) * rs2 * g2v.x + b2v.x);
  o[1] = f2b((xn[1] - mu2) * rs2 * g2v.y + b2v.y);
  o[2] = f2b((xn[2] - mu2) * rs2 * g2v.z + b2v.z);
  o[3] = f2b((xn[3] - mu2) * rs2 * g2v.w + b2v.w);
  *(u16x4*)(out + row * DM + t * 4) = o;
}

// single LN, f32 in, bf16 out
__global__ __launch_bounds__(256)
void ln_kernel(const float* __restrict__ x, const float* __restrict__ g,
               const float* __restrict__ b, u16* __restrict__ out)
{
  __shared__ float sred[8];
  const long row = blockIdx.x;
  const int t = threadIdx.x;
  const float4 xv = ((const float4*)(x + row * DM))[t];
  float s = xv.x + xv.y + xv.z + xv.w;
  float sq = xv.x * xv.x + xv.y * xv.y + xv.z * xv.z + xv.w * xv.w;
  blockReduce2(s, sq, sred);
  const float mu = s * (1.f / DM);
  const float rs = rsqrtf(sq * (1.f / DM) - mu * mu + 1e-5f);
  const float4 gv = ((const float4*)g)[t];
  const float4 bv = ((const float4*)b)[t];
  u16x4 o;
  o[0] = f2b((xv.x - mu) * rs * gv.x + bv.x);
  o[1] = f2b((xv.y - mu) * rs * gv.y + bv.y);
  o[2] = f2b((xv.z - mu) * rs * gv.z + bv.z);
  o[3] = f2b((xv.w - mu) * rs * gv.w + bv.w);
  *(u16x4*)(out + row * DM + t * 4) = o;
}

// ---------------- depthwise conv (k=3, pad 1 along L) + silu, vectorized ----------------
__global__ __launch_bounds__(256)
void conv_silu_kernel(const u16* __restrict__ x1, const float* __restrict__ w,
                      u16* __restrict__ xc)
{
  const long i8 = (long)blockIdx.x * 256 + threadIdx.x;  // NTOK*DM/8
  const long base = i8 * 8;
  const int d0 = (int)(base & (DM - 1));
  const long m = base >> 10;
  const int l = (int)(m & (SEQ - 1));
  const short8 cv = *(const short8*)(x1 + base);
  short8 lv = {}, rv = {};
  if (l > 0) lv = *(const short8*)(x1 + base - DM);
  if (l < SEQ - 1) rv = *(const short8*)(x1 + base + DM);
  short8 o;
#pragma unroll
  for (int j = 0; j < 8; ++j) {
    const int d = d0 + j;
    const float a = b2f((u16)lv[j]) * w[d * 3 + 0] + b2f((u16)cv[j]) * w[d * 3 + 1]
                  + b2f((u16)rv[j]) * w[d * 3 + 2];
    o[j] = (short)f2b(a / (1.f + __expf(-a)));
  }
  *(short8*)(xc + base) = o;
}

// ---------------- GEMM: C = A(MxK, bf16) * BT(NxK, bf16)^T ----------------
// 2-phase double-buffered, LDS slot-XOR swizzle (both sides), XCD-chunked bid swizzle.
// MODE 2: bf16 out = gelu_exact(acc + bias)
// MODE 3: f32  out = acc + bias + resid
// MODE 4: dtBC: ld 1152 f32; col<1024 softplus(+bias); col<1040 +bias2; col<1056 +bias3
// MODE 5: fused w1|v1 (N=2048): col<1024 -> outp (bf16, +bias); else silu -> outp2 (+bias2)
template <int MODE>
__global__ __launch_bounds__(256)
void gemm_bt(const u16* __restrict__ A, const u16* __restrict__ BT,
             const float* __restrict__ bias, const float* __restrict__ bias2,
             const float* __restrict__ bias3, const float* __restrict__ resid,
             void* __restrict__ outp, void* __restrict__ outp2,
             int K, int ldOut, int nbx)
{
  __shared__ u16 lds_a[2][4096];
  __shared__ u16 lds_b[2][4096];
  const int t = threadIdx.x;
  const int lane = t & 63;
  const int wid = t >> 6;
  const int wr = wid >> 1, wc = wid & 1;

  // XCD-chunked bijective swizzle (gridDim.x always a multiple of 8 here)
  int bid = blockIdx.x;
  const int qch = gridDim.x >> 3;
  bid = (bid & 7) * qch + (bid >> 3);
  const long brow = (long)(bid / nbx) * 128;
  const long bcol = (long)(bid % nbx) * 128;

  f32x4 acc[4][4] = {};

  // staging: thread t fills LDS 16B slot (row = t>>2, slot' = t&3); source slot is
  // slot' ^ ((row>>1)&3) so that the XOR-swizzled read below gets the right k-slot.
  const int srow = t >> 2;
  const int sslot = (t & 3) ^ ((t >> 3) & 3);
  const u16* aPtr = A + (brow + srow) * (long)K + sslot * 8;
  const u16* bPtr = BT + (bcol + srow) * (long)K + sslot * 8;
  u16* la = &lds_a[0][t * 8];
  u16* lb = &lds_b[0][t * 8];
  const long rowStep = 64L * K;
  const int nk = K >> 5;

  // read-side swizzled k-slot: global slot (lane>>4) lives at slot^((row>>1)&3);
  // (row>>1)&3 == ((lane&15)>>1)&3 for all fragment rows (row = wr*64+m*16+(lane&15)).
  const int rslot = (lane >> 4) ^ ((lane >> 1) & 3);
  const int koff = rslot * 8;
  const int arow = wr * 64 + (lane & 15);
  const int brw = wc * 64 + (lane & 15);

#define STAGE(kt, buf)                                              \
  {                                                                 \
    const int k0_ = (kt) << 5;                                      \
    gload16(aPtr + k0_, la + (buf) * 4096);                         \
    gload16(aPtr + rowStep + k0_, la + (buf) * 4096 + 2048);        \
    gload16(bPtr + k0_, lb + (buf) * 4096);                         \
    gload16(bPtr + rowStep + k0_, lb + (buf) * 4096 + 2048);        \
  }

  STAGE(0, 0);
  __syncthreads();
  int cur = 0;
  for (int kt = 0; kt < nk; ++kt) {
    if (kt + 1 < nk) STAGE(kt + 1, cur ^ 1);
    short8 af[4], bfr[4];
#pragma unroll
    for (int m = 0; m < 4; ++m)
      af[m] = *(const short8*)&lds_a[cur][(arow + m * 16) * 32 + koff];
#pragma unroll
    for (int n = 0; n < 4; ++n)
      bfr[n] = *(const short8*)&lds_b[cur][(brw + n * 16) * 32 + koff];
#pragma unroll
    for (int m = 0; m < 4; ++m)
#pragma unroll
      for (int n = 0; n < 4; ++n)
        acc[m][n] = __builtin_amdgcn_mfma_f32_16x16x32_bf16(af[m], bfr[n], acc[m][n], 0, 0, 0);
    __syncthreads();   // drains prefetch (vmcnt) + lds reads (lgkm)
    cur ^= 1;
  }
#undef STAGE

  const int cc = lane & 15;
  const int r0 = (lane >> 4) * 4;
#pragma unroll
  for (int m = 0; m < 4; ++m) {
#pragma unroll
    for (int n = 0; n < 4; ++n) {
      const long col = bcol + wc * 64 + n * 16 + cc;
#pragma unroll
      for (int r = 0; r < 4; ++r) {
        const long row = brow + wr * 64 + m * 16 + r0 + r;
        float val = acc[m][n][r];
        if constexpr (MODE == 4) {
          if (col < 1024) {
            val += bias[col];
            val = (val > 20.f) ? val : log1pf(__expf(val));
            ((float*)outp)[row * 1152 + col] = val;
          } else if (col < 1040) {
            ((float*)outp)[row * 1152 + col] = val + bias2[col - 1024];
          } else if (col < 1056) {
            ((float*)outp)[row * 1152 + col] = val + bias3[col - 1040];
          }
        } else if constexpr (MODE == 5) {
          if (col < 1024) {
            val += bias[col];
            ((u16*)outp)[row * 1024 + col] = f2b(val);
          } else {
            val += bias2[col - 1024];
            val = val / (1.f + __expf(-val));
            ((u16*)outp2)[row * 1024 + col - 1024] = f2b(val);
          }
        } else {
          val += bias[col];
          if constexpr (MODE == 2) val = 0.5f * val * (1.f + erff(val * 0.70710678118f));
          if constexpr (MODE == 3) {
            ((float*)outp)[row * ldOut + col] = val + resid[row * ldOut + col];
          } else {
            ((u16*)outp)[row * ldOut + col] = f2b(val);
          }
        }
      }
    }
  }
}

// ---------------- chunked selective scan ----------------
__global__ __launch_bounds__(256)
void scan_pass1(const u16* __restrict__ xc, const float* __restrict__ dtbc,
                const float* __restrict__ A_log, float* __restrict__ hloc,
                float* __restrict__ sdt)
{
  const int bx = blockIdx.x;
  const int b = bx >> 9;
  const int ch = (bx >> 4) & 31;
  const int dBase = (bx & 15) * 64;
  const int t = threadIdx.x;
  const int dl = t >> 2;
  const int q = t & 3;
  const int d = dBase + dl;

  __shared__ float s_b[32][16];
  __shared__ float s_dt[32][64];
  __shared__ u16 s_x[32][64];

  float Areg[4];
#pragma unroll
  for (int j = 0; j < 4; ++j) Areg[j] = -__expf(A_log[d * 16 + q * 4 + j]);
  float h[4] = {0.f, 0.f, 0.f, 0.f};
  float sAcc = 0.f;
  const long mBase = (long)b * SEQ + ch * CH;

  for (int c0 = 0; c0 < CH; c0 += 32) {
#pragma unroll
    for (int i = 0; i < 2; ++i) {
      int idx = i * 256 + t;
      int s = idx >> 4, j = idx & 15;
      s_b[s][j] = dtbc[(mBase + c0 + s) * 1152 + 1024 + j];
    }
#pragma unroll
    for (int i = 0; i < 8; ++i) {
      int idx = i * 256 + t;
      int s = idx >> 6, j = idx & 63;
      long m = mBase + c0 + s;
      s_dt[s][j] = dtbc[m * 1152 + dBase + j];
      s_x[s][j] = xc[m * DM + dBase + j];
    }
    __syncthreads();
#pragma unroll 4
    for (int s = 0; s < 32; ++s) {
      const float dt = s_dt[s][dl];
      const float p = dt * b2f(s_x[s][dl]);
      sAcc += dt;
#pragma unroll
      for (int j = 0; j < 4; ++j)
        h[j] = __expf(dt * Areg[j]) * h[j] + p * s_b[s][q * 4 + j];
    }
    __syncthreads();
  }
  const long base = (((long)b * NCH + ch) * 1024 + d) * 16 + q * 4;
  float4 hv; hv.x = h[0]; hv.y = h[1]; hv.z = h[2]; hv.w = h[3];
  *(float4*)&hloc[base] = hv;
  if (q == 0) sdt[((long)b * NCH + ch) * 1024 + d] = sAcc;
}

__global__ __launch_bounds__(256)
void scan_pass2(const float* __restrict__ A_log, const float* __restrict__ sdt,
                const float* __restrict__ hloc, float* __restrict__ hin)
{
  const int tid = blockIdx.x * 256 + threadIdx.x;
  const int b = tid >> 14;
  const int dn = tid & 16383;
  const int d = dn >> 4;
  const float A = -__expf(A_log[dn]);
  float h = 0.f;
  for (int c = 0; c < NCH; ++c) {
    const long idx = (((long)b * NCH + c) << 14) + dn;
    hin[idx] = h;
    h = __expf(A * sdt[((long)b * NCH + c) * 1024 + d]) * h + hloc[idx];
  }
}

__global__ __launch_bounds__(256)
void scan_pass3(const u16* __restrict__ xc, const float* __restrict__ dtbc,
                const u16* __restrict__ vg, const float* __restrict__ A_log,
                const float* __restrict__ D_p, const float* __restrict__ hin,
                u16* __restrict__ yv)
{
  const int bx = blockIdx.x;
  const int b = bx >> 9;
  const int ch = (bx >> 4) & 31;
  const int dBase = (bx & 15) * 64;
  const int t = threadIdx.x;
  const int dl = t >> 2;
  const int q = t & 3;
  const int d = dBase + dl;

  __shared__ float s_bc[32][32];
  __shared__ float s_dt[32][64];
  __shared__ u16 s_x[32][64];
  __shared__ u16 s_v[32][64];
  __shared__ u16 s_y[32][64];

  float Areg[4];
#pragma unroll
  for (int j = 0; j < 4; ++j) Areg[j] = -__expf(A_log[d * 16 + q * 4 + j]);
  const float Dp = D_p[d];
  const float4 hv = *(const float4*)&hin[(((long)b * NCH + ch) * 1024 + d) * 16 + q * 4];
  float h[4] = {hv.x, hv.y, hv.z, hv.w};

  const long mBase = (long)b * SEQ + ch * CH;

  for (int c0 = 0; c0 < CH; c0 += 32) {
#pragma unroll
    for (int i = 0; i < 4; ++i) {
      int idx = i * 256 + t;
      int s = idx >> 5, j = idx & 31;
      s_bc[s][j] = dtbc[(mBase + c0 + s) * 1152 + 1024 + j];
    }
#pragma unroll
    for (int i = 0; i < 8; ++i) {
      int idx = i * 256 + t;
      int s = idx >> 6, j = idx & 63;
      long m = mBase + c0 + s;
      s_dt[s][j] = dtbc[m * 1152 + dBase + j];
      s_x[s][j] = xc[m * DM + dBase + j];
      s_v[s][j] = vg[m * DM + dBase + j];
    }
    __syncthreads();
#pragma unroll 4
    for (int s = 0; s < 32; ++s) {
      const float dt = s_dt[s][dl];
      const float xt = b2f(s_x[s][dl]);
      const float p = dt * xt;
      float y = 0.f;
#pragma unroll
      for (int j = 0; j < 4; ++j) {
        const float dA = __expf(dt * Areg[j]);
        h[j] = dA * h[j] + p * s_bc[s][q * 4 + j];
        y = fmaf(h[j], s_bc[s][16 + q * 4 + j], y);
      }
      y += __shfl_xor(y, 1);
      y += __shfl_xor(y, 2);
      if (q == 0) s_y[s][dl] = f2b((y + Dp * xt) * b2f(s_v[s][dl]));
    }
    __syncthreads();
#pragma unroll
    for (int i = 0; i < 8; ++i) {
      int idx = i * 256 + t;
      int s = idx >> 6, j = idx & 63;
      yv[(mBase + c0 + s) * DM + dBase + j] = s_y[s][j];
    }
    __syncthreads();
  }
}

extern "C" void kernel_launch(void* const* d_in, const int* in_sizes, int n_in,
                              void* d_out, int out_size, void* d_ws, size_t ws_size,
                              hipStream_t stream)
{
  (void)in_sizes; (void)n_in; (void)out_size; (void)ws_size;
  const float* x      = (const float*)d_in[0];
  const float* ln1_g  = (const float*)d_in[1];
  const float* ln1_b  = (const float*)d_in[2];
  const float* ln_g   = (const float*)d_in[3];
  const float* ln_b   = (const float*)d_in[4];
  const float* w1_w   = (const float*)d_in[5];
  const float* w1_b   = (const float*)d_in[6];
  const float* v1_w   = (const float*)d_in[7];
  const float* v1_b   = (const float*)d_in[8];
  const float* w2_w   = (const float*)d_in[9];
  const float* w2_b   = (const float*)d_in[10];
  const float* conv_w = (const float*)d_in[11];
  const float* dt_w   = (const float*)d_in[12];
  const float* dt_b   = (const float*)d_in[13];
  const float* Bp_w   = (const float*)d_in[14];
  const float* Bp_b   = (const float*)d_in[15];
  const float* Cp_w   = (const float*)d_in[16];
  const float* Cp_b   = (const float*)d_in[17];
  const float* A_log  = (const float*)d_in[18];
  const float* D_p    = (const float*)d_in[19];
  const float* ln2_g  = (const float*)d_in[20];
  const float* ln2_b  = (const float*)d_in[21];
  const float* ff1_w  = (const float*)d_in[22];
  const float* ff1_b  = (const float*)d_in[23];
  const float* ff2_w  = (const float*)d_in[24];
  const float* ff2_b  = (const float*)d_in[25];

  char* ws = (char*)d_ws;
  size_t cur = 0;
  auto alloc = [&](size_t bytes) -> void* {
    void* p = ws + cur;
    cur = (cur + bytes + 255) & ~(size_t)255;
    return p;
  };

  u16* wv1T  = (u16*)alloc((size_t)2048 * 1024 * 2);   // [w1T ; v1T]
  u16* w2T   = (u16*)alloc((size_t)1024 * 1024 * 2);
  u16* wcatT = (u16*)alloc((size_t)1152 * 1024 * 2);
  u16* ff1T  = (u16*)alloc((size_t)3072 * 1024 * 2);
  u16* ff2T  = (u16*)alloc((size_t)1024 * 3072 * 2);
  u16* xm    = (u16*)alloc((size_t)NTOK * DM * 2);
  u16* x1b   = (u16*)alloc((size_t)NTOK * DM * 2);
  u16* vb    = (u16*)alloc((size_t)NTOK * DM * 2);
  u16* xcb   = (u16*)alloc((size_t)NTOK * DM * 2);
  float* dtbc = (float*)alloc((size_t)NTOK * 1152 * 4);
  float* x2  = (float*)alloc((size_t)NTOK * DM * 4);
  float* hloc = (float*)alloc((size_t)4 * NCH * 1024 * 16 * 4);  // 8 MB
  float* hin  = (float*)alloc((size_t)4 * NCH * 1024 * 16 * 4);  // 8 MB
  float* sdtb = (float*)alloc((size_t)4 * NCH * 1024 * 4);       // 512 KB
  u16* yvb  = xm;        // reuse: xm dead after fused GEMM
  u16* xn2  = x1b;       // reuse: x1 dead after conv
  u16* hb   = xcb;       // reuse: xc+dtbc dead after scan

  const dim3 tb32(32, 8);
  // weight prep
  wtrans<<<dim3(32, 32), tb32, 0, stream>>>(w1_w, wv1T, 1024, 1024, 0, 1024);
  wtrans<<<dim3(32, 32), tb32, 0, stream>>>(v1_w, wv1T, 1024, 1024, 1024, 1024);
  wtrans<<<dim3(32, 32), tb32, 0, stream>>>(w2_w, w2T, 1024, 1024, 0, 1024);
  wtrans<<<dim3(32, 32), tb32, 0, stream>>>(dt_w, wcatT, 1024, 1024, 0, 1024);
  small_trans<<<64, 256, 0, stream>>>(Bp_w, Cp_w, wcatT);
  hipMemsetAsync(wcatT + (size_t)1056 * 1024, 0, (size_t)96 * 1024 * 2, stream);
  wtrans<<<dim3(96, 32), tb32, 0, stream>>>(ff1_w, ff1T, 1024, 3072, 0, 1024);
  wtrans<<<dim3(32, 96), tb32, 0, stream>>>(ff2_w, ff2T, 3072, 1024, 0, 3072);

  // LN1 -> LN2 -> xm (bf16)
  ln_ln_kernel<<<NTOK, 256, 0, stream>>>(x, ln1_g, ln1_b, ln_g, ln_b, xm);

  // fused: x1 = xm @ w1 + b ; v = silu(xm @ v1 + b)   (N=2048)
  gemm_bt<5><<<1024, 256, 0, stream>>>(xm, wv1T, w1_b, v1_b, nullptr, nullptr,
                                       x1b, vb, 1024, 1024, 16);

  // xc = silu(depthwise_conv(x1))
  conv_silu_kernel<<<(NTOK * DM) / (256 * 8), 256, 0, stream>>>(x1b, conv_w, xcb);

  // dtBC = [softplus(xc@dt_w+dt_b) | xc@Bp_w+Bp_b | xc@Cp_w+Cp_b | pad]  (f32, ld 1152)
  gemm_bt<4><<<576, 256, 0, stream>>>(xcb, wcatT, dt_b, Bp_b, Cp_b, nullptr,
                                      dtbc, nullptr, 1024, 1152, 9);

  // chunked selective scan fused with y*v -> yv (bf16)
  scan_pass1<<<2048, 256, 0, stream>>>(xcb, dtbc, A_log, hloc, sdtb);
  scan_pass2<<<256, 256, 0, stream>>>(A_log, sdtb, hloc, hin);
  scan_pass3<<<2048, 256, 0, stream>>>(xcb, dtbc, vb, A_log, D_p, hin, yvb);

  // x2 = yv @ w2 + b + x (f32)
  gemm_bt<3><<<512, 256, 0, stream>>>(yvb, w2T, w2_b, nullptr, nullptr, x,
                                      x2, nullptr, 1024, 1024, 8);

  // xn2 = LN(x2) (bf16)
  ln_kernel<<<NTOK, 256, 0, stream>>>(x2, ln2_g, ln2_b, xn2);

  // h = gelu(xn2 @ ff1 + b) (bf16, ld 3072)
  gemm_bt<2><<<1536, 256, 0, stream>>>(xn2, ff1T, ff1_b, nullptr, nullptr, nullptr,
                                       hb, nullptr, 1024, 3072, 24);

  // out = h @ ff2 + b + x2 (f32)
  gemm_bt<3><<<512, 256, 0, stream>>>(hb, ff2T, ff2_b, nullptr, nullptr, x2,
                                      d_out, nullptr, 3072, 1024, 8);
}